// Round 4
// baseline (347.972 us; speedup 1.0000x reference)
//
#include <hip/hip_runtime.h>
#include <hip/hip_cooperative_groups.h>

namespace cg = cooperative_groups;

#define B_  32
#define C_  256
#define HID 64
#define HW  4096
#define F_  4

typedef float fvec4 __attribute__((ext_vector_type(4)));

// One cooperative kernel. 256 wgs x 256 threads (1 wg/CU).
// group g = wg & 7 (one XCD under round-robin dispatch - perf heuristic only),
// member m = wg >> 3 (0..31). Group g owns batches b = g*4+k, k=0..3.
// Per k: member m reduces channels c = m*8 .. m*8+7 (wave wv does planes
// m*8+wv*2, +1) -> spectral ; grid.sync ; each wg redundantly computes the
// MLP gate ; re-reads its SAME 8 planes (L2-hot) and writes out (nt-store).
__global__ __launch_bounds__(256) void fused_msa_kernel(
        const float* __restrict__ x, const float* __restrict__ w1,
        const float* __restrict__ w2, float* __restrict__ out,
        float* __restrict__ spec) {
    cg::grid_group grid = cg::this_grid();

    const int t    = threadIdx.x;
    const int w    = blockIdx.x;
    const int g    = w & 7;
    const int m    = w >> 3;
    const int wave = t >> 6;
    const int lane = t & 63;

    __shared__ float r0[64], r1[64];
    __shared__ float s[C_][F_];      // spectral[b] staged for MLP (4 KB)
    __shared__ float y[HID][F_];     // fc1 output (1 KB)
    __shared__ float gate_s[C_];     // gate vector (1 KB)

    if (t < 64) {
        float fh = (float)t;
        r0[t] = cosf(fh * 0.02454369260617026f) * 0.125f;               // pi/128
        r1[t] = cosf(fh * 0.07363107781851077f) * 0.17677669529663689f; // 3pi/128, sqrt(2/64)
    }
    __syncthreads();

    for (int k = 0; k < 4; ++k) {
        const int b = g * 4 + k;

        // ---------- phase 1: spectral for this wg's 8 channels ----------
        #pragma unroll
        for (int pp = 0; pp < 2; ++pp) {
            const int c = m * 8 + wave * 2 + pp;
            const fvec4* xv = (const fvec4*)(x + (size_t)(b * C_ + c) * HW);
            float f0 = 0.f, f1 = 0.f, f2 = 0.f, f3 = 0.f;
            #pragma unroll
            for (int q = 0; q < 16; ++q) {
                int v = q * 64 + lane;            // float4 index 0..1023
                fvec4 d = xv[v];                  // coalesced 1KB/wave
                int h  = v >> 4;
                int wb = (v & 15) << 2;
                float r0h = r0[h], r1h = r1[h];
                float e, t0, t1;
                e = d.x; t0 = e*r0[wb+0]; t1 = e*r1[wb+0];
                f0 += r0h*t0; f1 += r0h*t1; f2 += r1h*t0; f3 += r1h*t1;
                e = d.y; t0 = e*r0[wb+1]; t1 = e*r1[wb+1];
                f0 += r0h*t0; f1 += r0h*t1; f2 += r1h*t0; f3 += r1h*t1;
                e = d.z; t0 = e*r0[wb+2]; t1 = e*r1[wb+2];
                f0 += r0h*t0; f1 += r0h*t1; f2 += r1h*t0; f3 += r1h*t1;
                e = d.w; t0 = e*r0[wb+3]; t1 = e*r1[wb+3];
                f0 += r0h*t0; f1 += r0h*t1; f2 += r1h*t0; f3 += r1h*t1;
            }
            #pragma unroll
            for (int off = 32; off >= 1; off >>= 1) {
                f0 += __shfl_down(f0, off);
                f1 += __shfl_down(f1, off);
                f2 += __shfl_down(f2, off);
                f3 += __shfl_down(f3, off);
            }
            if (lane == 0) {
                float* sp = spec + ((size_t)b << 10) + (c << 2);
                // agent-scope stores: visible across XCDs regardless of L2 state
                __hip_atomic_store(&sp[0], f0, __ATOMIC_RELAXED, __HIP_MEMORY_SCOPE_AGENT);
                __hip_atomic_store(&sp[1], f1, __ATOMIC_RELAXED, __HIP_MEMORY_SCOPE_AGENT);
                __hip_atomic_store(&sp[2], f2, __ATOMIC_RELAXED, __HIP_MEMORY_SCOPE_AGENT);
                __hip_atomic_store(&sp[3], f3, __ATOMIC_RELAXED, __HIP_MEMORY_SCOPE_AGENT);
            }
        }

        __threadfence();
        grid.sync();

        // ---------- phase 2: MLP gate (computed redundantly per wg) ----------
        {
            const float* sb = spec + ((size_t)b << 10);
            s[t][0] = __hip_atomic_load(&sb[t*4+0], __ATOMIC_RELAXED, __HIP_MEMORY_SCOPE_AGENT);
            s[t][1] = __hip_atomic_load(&sb[t*4+1], __ATOMIC_RELAXED, __HIP_MEMORY_SCOPE_AGENT);
            s[t][2] = __hip_atomic_load(&sb[t*4+2], __ATOMIC_RELAXED, __HIP_MEMORY_SCOPE_AGENT);
            s[t][3] = __hip_atomic_load(&sb[t*4+3], __ATOMIC_RELAXED, __HIP_MEMORY_SCOPE_AGENT);
        }
        __syncthreads();
        {
            int h = t >> 2, f = t & 3;
            const float* w1r = w1 + h * C_;
            float a0 = 0.f, a1 = 0.f, a2 = 0.f, a3 = 0.f;
            #pragma unroll 4
            for (int c = 0; c < C_; c += 4) {
                a0 += s[c+0][f] * w1r[c+0];
                a1 += s[c+1][f] * w1r[c+1];
                a2 += s[c+2][f] * w1r[c+2];
                a3 += s[c+3][f] * w1r[c+3];
            }
            y[h][f] = fmaxf((a0 + a1) + (a2 + a3), 0.f);
        }
        __syncthreads();
        {
            int c = t;
            const float* w2r = w2 + c * HID;
            float a0 = 0.f, a1 = 0.f, a2 = 0.f, a3 = 0.f;
            #pragma unroll 8
            for (int h = 0; h < HID; ++h) {
                float wv = w2r[h];
                a0 += y[h][0]*wv; a1 += y[h][1]*wv; a2 += y[h][2]*wv; a3 += y[h][3]*wv;
            }
            float mm = (a0 + a1 + a2 + a3) * 0.25f;
            gate_s[c] = 1.f / (1.f + __expf(-mm));
        }
        __syncthreads();

        // ---------- phase 3: out = x * gate (re-read is L2/L3-hot) ----------
        #pragma unroll
        for (int pp = 0; pp < 2; ++pp) {
            const int c = m * 8 + wave * 2 + pp;
            const float gv = gate_s[c];
            const fvec4* xv = (const fvec4*)(x   + (size_t)(b * C_ + c) * HW);
            fvec4*       ov = (fvec4*)      (out + (size_t)(b * C_ + c) * HW);
            #pragma unroll
            for (int q = 0; q < 16; ++q) {
                fvec4 d = xv[q * 64 + lane];
                d *= gv;
                __builtin_nontemporal_store(d, ov + q * 64 + lane);
            }
        }
        // no sync before next k: next spectral writes go to a disjoint spec region
    }
}

extern "C" void kernel_launch(void* const* d_in, const int* in_sizes, int n_in,
                              void* d_out, int out_size, void* d_ws, size_t ws_size,
                              hipStream_t stream) {
    const float* x  = (const float*)d_in[0];
    const float* w1 = (const float*)d_in[1];
    const float* w2 = (const float*)d_in[2];
    float* out  = (float*)d_out;
    float* spec = (float*)d_ws;     // B*C*F = 32768 floats

    void* args[] = { (void*)&x, (void*)&w1, (void*)&w2, (void*)&out, (void*)&spec };
    hipLaunchCooperativeKernel((const void*)fused_msa_kernel,
                               dim3(256), dim3(256), args, 0, stream);
}

// Round 7
// 323.079 us; speedup vs baseline: 1.0770x; 1.0770x over previous
//
#include <hip/hip_runtime.h>
#include <hip/hip_cooperative_groups.h>

namespace cg = cooperative_groups;

#define B_  32
#define C_  256
#define HID 64
#define HW  4096
#define F_  4

typedef float fvec4 __attribute__((ext_vector_type(4)));

// One cooperative kernel: 256 wgs x 1024 threads (16 waves/CU).
// group g = wg & 7 (8 groups, XCD-aligned under round-robin dispatch - perf
// heuristic only), member m = wg >> 3 (0..31).
// Round r=0,1: group g handles batches b = g*4 + r*2 + {0,1}.
// Phase 1: each of the group's 512 waves reduces ONE full plane (16 float4
//   per lane, batched loads) -> spectral (agent stores).
// grid.sync. Phase 2: both batches' MLP gates computed redundantly per wg.
// Phase 3: each wave re-reads its SAME plane (cache-hot) * gate -> nt-store.
__global__ __launch_bounds__(1024, 4) void fused_msa_kernel(
        const float* __restrict__ x, const float* __restrict__ w1,
        const float* __restrict__ w2, float* __restrict__ out,
        float* __restrict__ spec) {
    cg::grid_group grid = cg::this_grid();

    const int t    = threadIdx.x;
    const int w    = blockIdx.x;
    const int g    = w & 7;
    const int m    = w >> 3;        // 0..31
    const int wave = t >> 6;        // 0..15
    const int lane = t & 63;
    const int wgm  = m * 16 + wave; // wave id within group: 0..511
    const int bsel = wgm >> 8;      // which of the group's 2 batches this round
    const int pl   = wgm & 255;     // plane (channel) this wave owns

    __shared__ float r0[64], r1[64];
    __shared__ float s[2][C_][F_];     // spectral tiles for 2 batches (8 KB)
    __shared__ float y[2][HID][F_];    // fc1 outputs (2 KB)
    __shared__ float gate_s[2][C_];    // gates (2 KB)

    if (t < 64) {
        float fh = (float)t;
        r0[t] = cosf(fh * 0.02454369260617026f) * 0.125f;               // pi/128
        r1[t] = cosf(fh * 0.07363107781851077f) * 0.17677669529663689f; // 3pi/128, sqrt(2/64)
    }
    __syncthreads();

    for (int r = 0; r < 2; ++r) {
        const int b = g * 4 + r * 2 + bsel;
        // fvec4-unit indexing: plane (b*C + pl) starts at (b*C+pl)*1024 fvec4
        const fvec4* xv = (const fvec4*)x + (size_t)(b * C_ + pl) * (HW / 4);

        // ---------- phase 1: full-plane spectral reduction, 16-deep loads ----
        {
            fvec4 d[16];
            #pragma unroll
            for (int q = 0; q < 16; ++q) d[q] = xv[q * 64 + lane];

            float f0 = 0.f, f1 = 0.f, f2 = 0.f, f3 = 0.f;
            #pragma unroll
            for (int q = 0; q < 16; ++q) {
                int v  = q * 64 + lane;           // float4 idx 0..1023
                int h  = v >> 4;
                int wb = (v & 15) << 2;
                float r0h = r0[h], r1h = r1[h];
                float e, t0, t1;
                e = d[q].x; t0 = e*r0[wb+0]; t1 = e*r1[wb+0];
                f0 += r0h*t0; f1 += r0h*t1; f2 += r1h*t0; f3 += r1h*t1;
                e = d[q].y; t0 = e*r0[wb+1]; t1 = e*r1[wb+1];
                f0 += r0h*t0; f1 += r0h*t1; f2 += r1h*t0; f3 += r1h*t1;
                e = d[q].z; t0 = e*r0[wb+2]; t1 = e*r1[wb+2];
                f0 += r0h*t0; f1 += r0h*t1; f2 += r1h*t0; f3 += r1h*t1;
                e = d[q].w; t0 = e*r0[wb+3]; t1 = e*r1[wb+3];
                f0 += r0h*t0; f1 += r0h*t1; f2 += r1h*t0; f3 += r1h*t1;
            }
            #pragma unroll
            for (int off = 32; off >= 1; off >>= 1) {
                f0 += __shfl_down(f0, off);
                f1 += __shfl_down(f1, off);
                f2 += __shfl_down(f2, off);
                f3 += __shfl_down(f3, off);
            }
            if (lane == 0) {
                float* sp = spec + ((size_t)b << 10) + (pl << 2);
                __hip_atomic_store(&sp[0], f0, __ATOMIC_RELAXED, __HIP_MEMORY_SCOPE_AGENT);
                __hip_atomic_store(&sp[1], f1, __ATOMIC_RELAXED, __HIP_MEMORY_SCOPE_AGENT);
                __hip_atomic_store(&sp[2], f2, __ATOMIC_RELAXED, __HIP_MEMORY_SCOPE_AGENT);
                __hip_atomic_store(&sp[3], f3, __ATOMIC_RELAXED, __HIP_MEMORY_SCOPE_AGENT);
            }
        }

        __threadfence();
        grid.sync();

        // ---------- phase 2: MLP gates for BOTH batches (redundant per wg) ----
        if (t < 512) {
            int bi = t >> 8, tt = t & 255;
            const float* sb = spec + ((size_t)(g * 4 + r * 2 + bi) << 10);
            s[bi][tt][0] = __hip_atomic_load(&sb[tt*4+0], __ATOMIC_RELAXED, __HIP_MEMORY_SCOPE_AGENT);
            s[bi][tt][1] = __hip_atomic_load(&sb[tt*4+1], __ATOMIC_RELAXED, __HIP_MEMORY_SCOPE_AGENT);
            s[bi][tt][2] = __hip_atomic_load(&sb[tt*4+2], __ATOMIC_RELAXED, __HIP_MEMORY_SCOPE_AGENT);
            s[bi][tt][3] = __hip_atomic_load(&sb[tt*4+3], __ATOMIC_RELAXED, __HIP_MEMORY_SCOPE_AGENT);
        }
        __syncthreads();
        if (t < 512) {                       // fc1 + relu: (bi, h, f)
            int bi = t >> 8, tt = t & 255;
            int h = tt >> 2, f = tt & 3;
            const float* w1r = w1 + h * C_;
            float a0 = 0.f, a1 = 0.f, a2 = 0.f, a3 = 0.f;
            #pragma unroll 4
            for (int cc = 0; cc < C_; cc += 4) {
                a0 += s[bi][cc+0][f] * w1r[cc+0];
                a1 += s[bi][cc+1][f] * w1r[cc+1];
                a2 += s[bi][cc+2][f] * w1r[cc+2];
                a3 += s[bi][cc+3][f] * w1r[cc+3];
            }
            y[bi][h][f] = fmaxf((a0 + a1) + (a2 + a3), 0.f);
        }
        __syncthreads();
        if (t < 512) {                       // fc2 + mean + sigmoid: (bi, c)
            int bi = t >> 8, c = t & 255;
            const float* w2r = w2 + c * HID;
            float a0 = 0.f, a1 = 0.f, a2 = 0.f, a3 = 0.f;
            #pragma unroll 8
            for (int h = 0; h < HID; ++h) {
                float wv = w2r[h];
                a0 += y[bi][h][0]*wv; a1 += y[bi][h][1]*wv;
                a2 += y[bi][h][2]*wv; a3 += y[bi][h][3]*wv;
            }
            float mm = (a0 + a1 + a2 + a3) * 0.25f;
            gate_s[bi][c] = 1.f / (1.f + __expf(-mm));
        }
        __syncthreads();

        // ---------- phase 3: out = x * gate (re-read is cache-hot) ----------
        {
            const float gv = gate_s[bsel][pl];
            fvec4* ov = (fvec4*)out + (size_t)(b * C_ + pl) * (HW / 4);
            #pragma unroll
            for (int q = 0; q < 16; ++q) {
                fvec4 d = xv[q * 64 + lane];
                d *= gv;
                __builtin_nontemporal_store(d, ov + q * 64 + lane);
            }
        }
        // next round: phase 1 writes a disjoint spec region; the grid.sync
        // (which is also a block barrier) orders phase-3 reads of gate_s
        // before phase-2 rewrites s/y/gate_s.
    }
}

extern "C" void kernel_launch(void* const* d_in, const int* in_sizes, int n_in,
                              void* d_out, int out_size, void* d_ws, size_t ws_size,
                              hipStream_t stream) {
    const float* x  = (const float*)d_in[0];
    const float* w1 = (const float*)d_in[1];
    const float* w2 = (const float*)d_in[2];
    float* out  = (float*)d_out;
    float* spec = (float*)d_ws;     // B*C*F = 32768 floats

    void* args[] = { (void*)&x, (void*)&w1, (void*)&w2, (void*)&out, (void*)&spec };
    hipLaunchCooperativeKernel((const void*)fused_msa_kernel,
                               dim3(256), dim3(1024), args, 0, stream);
}

// Round 8
// 84.236 us; speedup vs baseline: 4.1309x; 3.8354x over previous
//
#include <hip/hip_runtime.h>

#define B_  32
#define C_  256
#define HID 64
#define HW  4096
#define F_  4
#define CHUNK_B 16          // batches per chunk (2 chunks total)

typedef float fvec4 __attribute__((ext_vector_type(4)));

// ---------------- Kernel 1: spectral[b,c,f] for one chunk of batches
// basis f0 = r0[h]*r0[w], f1 = r0[h]*r1[w], f2 = r1[h]*r0[w], f3 = r1[h]*r1[w]
// r0[j] = cos(pi*j/128)*0.125, r1[j] = cos(3*pi*j/128)*sqrt(2/64)
__global__ __launch_bounds__(256) void spectral_kernel(
        const float* __restrict__ x, float* __restrict__ spectral, int b0) {
    const int plane = b0 * C_ + blockIdx.x;     // global b*C + c
    const int t = threadIdx.x;                  // 0..255

    __shared__ float r0[64], r1[64];
    if (t < 64) {
        float fh = (float)t;
        r0[t] = cosf(fh * 0.02454369260617026f) * 0.125f;               // pi/128
        r1[t] = cosf(fh * 0.07363107781851077f) * 0.17677669529663689f; // 3pi/128, sqrt(2/64)
    }
    __syncthreads();

    const fvec4* xv = (const fvec4*)x + (size_t)plane * (HW / 4);
    float f0 = 0.f, f1 = 0.f, f2 = 0.f, f3 = 0.f;

    #pragma unroll
    for (int q = 0; q < 4; ++q) {
        int v = q * 256 + t;              // fvec4 index within plane (0..1023)
        fvec4 d = xv[v];                  // coalesced
        int h  = v >> 4;                  // 16 fvec4 per row
        int wb = (v & 15) << 2;
        float r0h = r0[h], r1h = r1[h];
        float e, t0, t1;
        e = d.x; t0 = e * r0[wb+0]; t1 = e * r1[wb+0];
        f0 += r0h*t0; f1 += r0h*t1; f2 += r1h*t0; f3 += r1h*t1;
        e = d.y; t0 = e * r0[wb+1]; t1 = e * r1[wb+1];
        f0 += r0h*t0; f1 += r0h*t1; f2 += r1h*t0; f3 += r1h*t1;
        e = d.z; t0 = e * r0[wb+2]; t1 = e * r1[wb+2];
        f0 += r0h*t0; f1 += r0h*t1; f2 += r1h*t0; f3 += r1h*t1;
        e = d.w; t0 = e * r0[wb+3]; t1 = e * r1[wb+3];
        f0 += r0h*t0; f1 += r0h*t1; f2 += r1h*t0; f3 += r1h*t1;
    }

    // wave (64-lane) reduction
    #pragma unroll
    for (int off = 32; off >= 1; off >>= 1) {
        f0 += __shfl_down(f0, off);
        f1 += __shfl_down(f1, off);
        f2 += __shfl_down(f2, off);
        f3 += __shfl_down(f3, off);
    }
    __shared__ float part[4][F_];
    int wave = t >> 6, lane = t & 63;
    if (lane == 0) { part[wave][0]=f0; part[wave][1]=f1; part[wave][2]=f2; part[wave][3]=f3; }
    __syncthreads();
    if (t == 0) {
        fvec4 s;
        s.x = part[0][0]+part[1][0]+part[2][0]+part[3][0];
        s.y = part[0][1]+part[1][1]+part[2][1]+part[3][1];
        s.z = part[0][2]+part[1][2]+part[2][2]+part[3][2];
        s.w = part[0][3]+part[1][3]+part[2][3]+part[3][3];
        ((fvec4*)spectral)[plane] = s;
    }
}

// ---------------- Kernel 2: per-batch MLP + sigmoid gate (one chunk)
__global__ __launch_bounds__(256) void gate_kernel(
        const float* __restrict__ spectral, const float* __restrict__ w1,
        const float* __restrict__ w2, float* __restrict__ gate, int b0) {
    const int b = b0 + blockIdx.x;
    const int t = threadIdx.x;

    __shared__ float s[C_][F_];     // 4 KB
    __shared__ float y[HID][F_];    // 1 KB

    ((fvec4*)&s[0][0])[t] = ((const fvec4*)(spectral + (size_t)b * C_ * F_))[t];
    __syncthreads();

    {   // fc1 + relu: thread t -> (h = t/4, f = t%4)
        int h = t >> 2, f = t & 3;
        const float* w1r = w1 + h * C_;
        float a0 = 0.f, a1 = 0.f, a2 = 0.f, a3 = 0.f;
        #pragma unroll 4
        for (int c = 0; c < C_; c += 4) {
            a0 += s[c+0][f] * w1r[c+0];
            a1 += s[c+1][f] * w1r[c+1];
            a2 += s[c+2][f] * w1r[c+2];
            a3 += s[c+3][f] * w1r[c+3];
        }
        y[h][f] = fmaxf((a0 + a1) + (a2 + a3), 0.f);
    }
    __syncthreads();

    {   // fc2 + mean + sigmoid: thread t -> channel c
        const float* w2r = w2 + t * HID;
        float a0=0.f, a1=0.f, a2=0.f, a3=0.f;
        #pragma unroll 8
        for (int h = 0; h < HID; ++h) {
            float wv = w2r[h];
            a0 += y[h][0]*wv; a1 += y[h][1]*wv; a2 += y[h][2]*wv; a3 += y[h][3]*wv;
        }
        float m = (a0 + a1 + a2 + a3) * 0.25f;
        gate[b * C_ + t] = 1.f / (1.f + __expf(-m));
    }
}

// ---------------- Kernel 3: out = x * gate[b,c] (one chunk; x-read is L3-hot)
__global__ __launch_bounds__(256) void scale_kernel(
        const float* __restrict__ x, const float* __restrict__ gate,
        float* __restrict__ out, long long start4, long long n4) {
    long long i = start4 + (long long)blockIdx.x * 256 + threadIdx.x;
    const long long end = start4 + n4;
    const long long stride = (long long)gridDim.x * 256;
    for (; i < end; i += stride) {
        fvec4 v = ((const fvec4*)x)[i];
        float g = gate[i >> 10];     // 1024 fvec4 per (b,c) plane
        v *= g;
        __builtin_nontemporal_store(v, ((fvec4*)out) + i);
    }
}

extern "C" void kernel_launch(void* const* d_in, const int* in_sizes, int n_in,
                              void* d_out, int out_size, void* d_ws, size_t ws_size,
                              hipStream_t stream) {
    const float* x  = (const float*)d_in[0];
    const float* w1 = (const float*)d_in[1];
    const float* w2 = (const float*)d_in[2];
    float* out = (float*)d_out;

    float* spectral = (float*)d_ws;                         // B*C*F = 32768 floats
    float* gate     = (float*)d_ws + (size_t)B_ * C_ * F_;  // B*C   = 8192 floats

    const long long chunk4 = (long long)CHUNK_B * C_ * HW / 4;   // 4,194,304

    for (int chunk = 0; chunk < B_ / CHUNK_B; ++chunk) {
        const int b0 = chunk * CHUNK_B;
        spectral_kernel<<<CHUNK_B * C_, 256, 0, stream>>>(x, spectral, b0);
        gate_kernel<<<CHUNK_B, 256, 0, stream>>>(spectral, w1, w2, gate, b0);
        scale_kernel<<<2048, 256, 0, stream>>>(x, gate, out,
                                               (long long)b0 * C_ * HW / 4, chunk4);
    }
}

// Round 9
// 74.011 us; speedup vs baseline: 4.7016x; 1.1382x over previous
//
#include <hip/hip_runtime.h>

#define B_  32
#define C_  256
#define HID 64
#define HW  4096
#define F_  4

typedef float fvec4 __attribute__((ext_vector_type(4)));

// ---------------- Kernel 1: spectral[b,c,f] = sum_{h,w} x[b,c,h,w]*basis[f,h,w]
// basis f0 = r0[h]*r0[w], f1 = r0[h]*r1[w], f2 = r1[h]*r0[w], f3 = r1[h]*r1[w]
// r0[j] = cos(pi*j/128)*0.125, r1[j] = cos(3*pi*j/128)*sqrt(2/64)
__global__ __launch_bounds__(256) void spectral_kernel(
        const float* __restrict__ x, float* __restrict__ spectral) {
    const int plane = blockIdx.x;               // b*C + c
    const int t = threadIdx.x;                  // 0..255

    __shared__ float r0[64], r1[64];
    if (t < 64) {
        float fh = (float)t;
        r0[t] = cosf(fh * 0.02454369260617026f) * 0.125f;               // pi/128
        r1[t] = cosf(fh * 0.07363107781851077f) * 0.17677669529663689f; // 3pi/128, sqrt(2/64)
    }
    __syncthreads();

    const fvec4* xv = (const fvec4*)x + (size_t)plane * (HW / 4);
    float f0 = 0.f, f1 = 0.f, f2 = 0.f, f3 = 0.f;

    #pragma unroll
    for (int q = 0; q < 4; ++q) {
        int v = q * 256 + t;              // fvec4 index within plane (0..1023)
        fvec4 d = xv[v];                  // coalesced
        int h  = v >> 4;                  // 16 fvec4 per row
        int wb = (v & 15) << 2;
        float r0h = r0[h], r1h = r1[h];
        float e, t0, t1;
        e = d.x; t0 = e * r0[wb+0]; t1 = e * r1[wb+0];
        f0 += r0h*t0; f1 += r0h*t1; f2 += r1h*t0; f3 += r1h*t1;
        e = d.y; t0 = e * r0[wb+1]; t1 = e * r1[wb+1];
        f0 += r0h*t0; f1 += r0h*t1; f2 += r1h*t0; f3 += r1h*t1;
        e = d.z; t0 = e * r0[wb+2]; t1 = e * r1[wb+2];
        f0 += r0h*t0; f1 += r0h*t1; f2 += r1h*t0; f3 += r1h*t1;
        e = d.w; t0 = e * r0[wb+3]; t1 = e * r1[wb+3];
        f0 += r0h*t0; f1 += r0h*t1; f2 += r1h*t0; f3 += r1h*t1;
    }

    #pragma unroll
    for (int off = 32; off >= 1; off >>= 1) {
        f0 += __shfl_down(f0, off);
        f1 += __shfl_down(f1, off);
        f2 += __shfl_down(f2, off);
        f3 += __shfl_down(f3, off);
    }
    __shared__ float part[4][F_];
    int wave = t >> 6, lane = t & 63;
    if (lane == 0) { part[wave][0]=f0; part[wave][1]=f1; part[wave][2]=f2; part[wave][3]=f3; }
    __syncthreads();
    if (t == 0) {
        fvec4 s;
        s.x = part[0][0]+part[1][0]+part[2][0]+part[3][0];
        s.y = part[0][1]+part[1][1]+part[2][1]+part[3][1];
        s.z = part[0][2]+part[1][2]+part[2][2]+part[3][2];
        s.w = part[0][3]+part[1][3]+part[2][3]+part[3][3];
        ((fvec4*)spectral)[plane] = s;
    }
}

// ---------------- Kernel 2 (fused gate + scale):
// block j -> batch b = j/64, planes c0 = (j&63)*4 .. +3.
// All 256 threads compute the batch's MLP gate redundantly (weights are
// L2-resident: 128 KB total, shared by 64 blocks/batch), then stream 4 planes.
__global__ __launch_bounds__(256) void gate_scale_kernel(
        const float* __restrict__ x, const float* __restrict__ spectral,
        const float* __restrict__ w1, const float* __restrict__ w2,
        float* __restrict__ out) {
    const int j  = blockIdx.x;
    const int b  = j >> 6;
    const int c0 = (j & 63) << 2;
    const int t  = threadIdx.x;

    __shared__ float s[C_][F_];    // spectral[b] (4 KB)
    __shared__ float y[HID][F_];   // fc1 output (1 KB)
    __shared__ float g4[4];        // the 4 gates this block needs

    ((fvec4*)&s[0][0])[t] = ((const fvec4*)spectral)[b * C_ + t];
    __syncthreads();

    {   // fc1 + relu: thread t -> (h = t/4, f = t%4), 256 MACs
        int h = t >> 2, f = t & 3;
        const float* w1r = w1 + h * C_;
        float a0 = 0.f, a1 = 0.f, a2 = 0.f, a3 = 0.f;
        #pragma unroll 4
        for (int c = 0; c < C_; c += 4) {
            a0 += s[c+0][f] * w1r[c+0];
            a1 += s[c+1][f] * w1r[c+1];
            a2 += s[c+2][f] * w1r[c+2];
            a3 += s[c+3][f] * w1r[c+3];
        }
        y[h][f] = fmaxf((a0 + a1) + (a2 + a3), 0.f);
    }
    __syncthreads();

    {   // fc2 + mean + sigmoid for the block's 4 channels: wave w -> channel
        // c0+w; lane h: v = w2[c,h] * 0.25*sum_f y[h][f]; wave-reduce.
        int wv = t >> 6, lane = t & 63;
        int c = c0 + wv;
        float v = w2[c * HID + lane] *
                  (0.25f * ((y[lane][0] + y[lane][1]) + (y[lane][2] + y[lane][3])));
        #pragma unroll
        for (int off = 32; off >= 1; off >>= 1) v += __shfl_down(v, off);
        if (lane == 0) g4[wv] = 1.f / (1.f + __expf(-v));
    }
    __syncthreads();

    // stream 4 planes: 4096 fvec4, 16 iters x 256 threads
    const fvec4* xv = (const fvec4*)x   + (size_t)(b * C_ + c0) * (HW / 4);
    fvec4*       ov = (fvec4*)      out + (size_t)(b * C_ + c0) * (HW / 4);
    #pragma unroll
    for (int q = 0; q < 16; ++q) {
        int i = q * 256 + t;          // 0..4095
        fvec4 d = xv[i];
        d *= g4[i >> 10];
        __builtin_nontemporal_store(d, ov + i);
    }
}

extern "C" void kernel_launch(void* const* d_in, const int* in_sizes, int n_in,
                              void* d_out, int out_size, void* d_ws, size_t ws_size,
                              hipStream_t stream) {
    const float* x  = (const float*)d_in[0];
    const float* w1 = (const float*)d_in[1];
    const float* w2 = (const float*)d_in[2];
    float* out = (float*)d_out;

    float* spectral = (float*)d_ws;     // B*C*F = 32768 floats

    spectral_kernel<<<B_ * C_, 256, 0, stream>>>(x, spectral);
    gate_scale_kernel<<<B_ * C_ / 4, 256, 0, stream>>>(x, spectral, w1, w2, out);
}

// Round 11
// 73.405 us; speedup vs baseline: 4.7405x; 1.0083x over previous
//
#include <hip/hip_runtime.h>

#define B_  32
#define C_  256
#define HID 64
#define HW  4096
#define F_  4

typedef float fvec4 __attribute__((ext_vector_type(4)));

// ---------------- Kernel 1: spectral[b,c,f] = sum_{h,w} x[b,c,h,w]*basis[f,h,w]
// basis f0 = r0[h]*r0[w], f1 = r0[h]*r1[w], f2 = r1[h]*r0[w], f3 = r1[h]*r1[w]
// r0[j] = cos(pi*j/128)*0.125, r1[j] = cos(3*pi*j/128)*sqrt(2/64)
__global__ __launch_bounds__(256) void spectral_kernel(
        const float* __restrict__ x, float* __restrict__ spectral) {
    const int plane = blockIdx.x;               // b*C + c
    const int t = threadIdx.x;                  // 0..255

    __shared__ float r0[64], r1[64];
    if (t < 64) {
        float fh = (float)t;
        r0[t] = cosf(fh * 0.02454369260617026f) * 0.125f;               // pi/128
        r1[t] = cosf(fh * 0.07363107781851077f) * 0.17677669529663689f; // 3pi/128, sqrt(2/64)
    }
    __syncthreads();

    const fvec4* xv = (const fvec4*)x + (size_t)plane * (HW / 4);
    float f0 = 0.f, f1 = 0.f, f2 = 0.f, f3 = 0.f;

    #pragma unroll
    for (int q = 0; q < 4; ++q) {
        int v = q * 256 + t;              // fvec4 index within plane (0..1023)
        fvec4 d = xv[v];                  // coalesced
        int h  = v >> 4;                  // 16 fvec4 per row
        int wb = (v & 15) << 2;
        float r0h = r0[h], r1h = r1[h];
        float e, t0, t1;
        e = d.x; t0 = e * r0[wb+0]; t1 = e * r1[wb+0];
        f0 += r0h*t0; f1 += r0h*t1; f2 += r1h*t0; f3 += r1h*t1;
        e = d.y; t0 = e * r0[wb+1]; t1 = e * r1[wb+1];
        f0 += r0h*t0; f1 += r0h*t1; f2 += r1h*t0; f3 += r1h*t1;
        e = d.z; t0 = e * r0[wb+2]; t1 = e * r1[wb+2];
        f0 += r0h*t0; f1 += r0h*t1; f2 += r1h*t0; f3 += r1h*t1;
        e = d.w; t0 = e * r0[wb+3]; t1 = e * r1[wb+3];
        f0 += r0h*t0; f1 += r0h*t1; f2 += r1h*t0; f3 += r1h*t1;
    }

    #pragma unroll
    for (int off = 32; off >= 1; off >>= 1) {
        f0 += __shfl_down(f0, off);
        f1 += __shfl_down(f1, off);
        f2 += __shfl_down(f2, off);
        f3 += __shfl_down(f3, off);
    }
    __shared__ float part[4][F_];
    int wave = t >> 6, lane = t & 63;
    if (lane == 0) { part[wave][0]=f0; part[wave][1]=f1; part[wave][2]=f2; part[wave][3]=f3; }
    __syncthreads();
    if (t == 0) {
        fvec4 s;
        s.x = part[0][0]+part[1][0]+part[2][0]+part[3][0];
        s.y = part[0][1]+part[1][1]+part[2][1]+part[3][1];
        s.z = part[0][2]+part[1][2]+part[2][2]+part[3][2];
        s.w = part[0][3]+part[1][3]+part[2][3]+part[3][3];
        ((fvec4*)spectral)[plane] = s;
    }
}

// ---------------- Kernel 2: per-batch MLP + sigmoid gate
__global__ __launch_bounds__(256) void gate_kernel(
        const float* __restrict__ spectral, const float* __restrict__ w1,
        const float* __restrict__ w2, float* __restrict__ gate) {
    const int b = blockIdx.x;
    const int t = threadIdx.x;

    __shared__ float s[C_][F_];     // 4 KB
    __shared__ float y[HID][F_];    // 1 KB

    ((fvec4*)&s[0][0])[t] = ((const fvec4*)(spectral + (size_t)b * C_ * F_))[t];
    __syncthreads();

    {   // fc1 + relu: thread t -> (h = t/4, f = t%4)
        int h = t >> 2, f = t & 3;
        const float* w1r = w1 + h * C_;
        float a0 = 0.f, a1 = 0.f, a2 = 0.f, a3 = 0.f;
        #pragma unroll 4
        for (int c = 0; c < C_; c += 4) {
            a0 += s[c+0][f] * w1r[c+0];
            a1 += s[c+1][f] * w1r[c+1];
            a2 += s[c+2][f] * w1r[c+2];
            a3 += s[c+3][f] * w1r[c+3];
        }
        y[h][f] = fmaxf((a0 + a1) + (a2 + a3), 0.f);
    }
    __syncthreads();

    {   // fc2 + mean + sigmoid: thread t -> channel c
        const float* w2r = w2 + t * HID;
        float a0=0.f, a1=0.f, a2=0.f, a3=0.f;
        #pragma unroll 8
        for (int h = 0; h < HID; ++h) {
            float wv = w2r[h];
            a0 += y[h][0]*wv; a1 += y[h][1]*wv; a2 += y[h][2]*wv; a3 += y[h][3]*wv;
        }
        float m = (a0 + a1 + a2 + a3) * 0.25f;
        gate[b * C_ + t] = 1.f / (1.f + __expf(-m));
    }
}

// ---------------- Kernel 3: out = x * gate[b,c], exact cover, loop-free.
// 8192 blocks x 256 threads x 4 fvec4 = 8,388,608 fvec4 = whole tensor.
// Slice stride S = 8192*256 fvec4 = 2048 planes. Within a block the plane
// index (base+kS)>>10 is uniform: gi + k*2048, gi = blockIdx>>2 -> scalar
// gate loads (4 blocks per plane; blocks never straddle a plane boundary).
__global__ __launch_bounds__(256) void scale_kernel(
        const float* __restrict__ x, const float* __restrict__ gate,
        float* __restrict__ out) {
    const long long base = (long long)blockIdx.x * 256 + threadIdx.x;
    const long long S = 8192LL * 256;            // fvec4 stride per k
    const int gi = blockIdx.x >> 2;              // plane of k=0 slice

    const fvec4* xv = (const fvec4*)x;
    fvec4*       ov = (fvec4*)out;

    fvec4 d0 = __builtin_nontemporal_load(xv + base);
    fvec4 d1 = __builtin_nontemporal_load(xv + base + S);
    fvec4 d2 = __builtin_nontemporal_load(xv + base + 2*S);
    fvec4 d3 = __builtin_nontemporal_load(xv + base + 3*S);

    const float g0 = gate[gi];
    const float g1 = gate[gi + 2048];
    const float g2 = gate[gi + 4096];
    const float g3 = gate[gi + 6144];

    d0 *= g0; d1 *= g1; d2 *= g2; d3 *= g3;

    __builtin_nontemporal_store(d0, ov + base);
    __builtin_nontemporal_store(d1, ov + base + S);
    __builtin_nontemporal_store(d2, ov + base + 2*S);
    __builtin_nontemporal_store(d3, ov + base + 3*S);
}

extern "C" void kernel_launch(void* const* d_in, const int* in_sizes, int n_in,
                              void* d_out, int out_size, void* d_ws, size_t ws_size,
                              hipStream_t stream) {
    const float* x  = (const float*)d_in[0];
    const float* w1 = (const float*)d_in[1];
    const float* w2 = (const float*)d_in[2];
    float* out = (float*)d_out;

    float* spectral = (float*)d_ws;                         // B*C*F = 32768 floats
    float* gate     = (float*)d_ws + (size_t)B_ * C_ * F_;  // B*C   = 8192 floats

    spectral_kernel<<<B_ * C_, 256, 0, stream>>>(x, spectral);
    gate_kernel<<<B_, 256, 0, stream>>>(spectral, w1, w2, gate);
    scale_kernel<<<8192, 256, 0, stream>>>(x, gate, out);
}